// Round 1
// baseline (1345.115 us; speedup 1.0000x reference)
//
#include <hip/hip_runtime.h>
#include <hip/hip_bf16.h>
#include <stdint.h>

typedef __attribute__((ext_vector_type(8))) short short8;
typedef __attribute__((ext_vector_type(4))) float floatx4;

namespace {

constexpr int  BB  = 16;    // batch
constexpr int  E_  = 8;     // experts
constexpr int  CAP = 1024;  // capacity per expert (EC/E)
constexpr int  D_  = 512;   // d_model
constexpr int  F_  = 2048;  // d_ff
constexpr long EC_ = (long)E_ * CAP;   // 8192
constexpr long M_  = (long)BB * CAP;   // 16384 rows per expert

constexpr int BM = 128, BN = 128, BK = 32;

static_assert(M_ % BM == 0 && F_ % BN == 0 && D_ % BN == 0, "tile divisibility");
static_assert(D_ % BK == 0 && F_ % BK == 0, "K divisibility");

__device__ __forceinline__ float gelu_tanh(float x) {
    // jax.nn.gelu default: approximate=True (tanh form)
    const float k0 = 0.7978845608028654f;  // sqrt(2/pi)
    const float k1 = 0.044715f;
    float u = k0 * x * (1.0f + k1 * x * x);
    // tanh(u) = 1 - 2/(exp(2u)+1)
    float t = 1.0f - 2.0f / (__expf(2.0f * u) + 1.0f);
    return 0.5f * x * (1.0f + t);
}

// Generic B^T GEMM over one expert-sliced problem.
//   A rows:  addr = e*sAe + b*sAb + c*K       (m = b*CAP + c, row length == K)
//   B rows:  addr = e*sBe + n*ldb + k         (N x K, k-contiguous)
//   Out:     addr = e*sOe + b*sOb + c*ldo + n
// EPI: 0 = +bias, gelu, bf16 store   1 = +bias, f32 store   2 = f32 accumulate (no bias)
template <int EPI>
__global__ __launch_bounds__(256, 2) void gemm_bt(
    const __hip_bfloat16* __restrict__ A,
    const __hip_bfloat16* __restrict__ Bt,
    const float* __restrict__ bias, void* __restrict__ Out,
    const int K, const int ldb, const int ldo,
    const long sAb, const long sAe,
    const long sBe, const int biasE,
    const long sOb, const long sOe)
{
    __shared__ __align__(16) __hip_bfloat16 As[BM * BK];
    __shared__ __align__(16) __hip_bfloat16 Bs[BN * BK];

    const int e  = blockIdx.z;
    const int m0 = blockIdx.y * BM;
    const int n0 = blockIdx.x * BN;

    const int tid  = threadIdx.x;
    const int wave = tid >> 6;
    const int lane = tid & 63;

    // staging: each 1024B wave-instruction covers 16 rows (64B/row)
    const int srow = lane >> 2;        // row within a 16-row chunk
    const int sk   = (lane & 3) * 8;   // element offset within a row (8 bf16 = 16B)

    const __hip_bfloat16* Ae = A  + (long)e * sAe;
    const __hip_bfloat16* Be = Bt + (long)e * sBe + (long)n0 * ldb;

    floatx4 acc[4][4] = {};

    const int wm = (wave >> 1) * 64;   // wave's m offset in tile
    const int wn = (wave & 1) * 64;    // wave's n offset in tile
    const int fr = lane & 15;          // fragment row/col index
    const int fq = lane >> 4;          // quad -> k = fq*8

    for (int k0 = 0; k0 < K; k0 += BK) {
#pragma unroll
        for (int t = 0; t < 2; ++t) {
            const int ch = wave * 2 + t;
            const int mg = m0 + ch * 16 + srow;
            const int b  = mg >> 10;            // CAP = 1024
            const int c  = mg & (CAP - 1);
            const __hip_bfloat16* gp = Ae + (long)b * sAb + (long)c * K + (k0 + sk);
            __builtin_amdgcn_global_load_lds(
                (const __attribute__((address_space(1))) void*)gp,
                (__attribute__((address_space(3))) void*)((char*)As + ch * 1024),
                16, 0, 0);
        }
#pragma unroll
        for (int t = 0; t < 2; ++t) {
            const int ch = wave * 2 + t;
            const int nr = ch * 16 + srow;
            const __hip_bfloat16* gp = Be + (long)nr * ldb + (k0 + sk);
            __builtin_amdgcn_global_load_lds(
                (const __attribute__((address_space(1))) void*)gp,
                (__attribute__((address_space(3))) void*)((char*)Bs + ch * 1024),
                16, 0, 0);
        }
        __syncthreads();

        short8 af[4], bf[4];
#pragma unroll
        for (int i = 0; i < 4; ++i)
            af[i] = *(const short8*)(As + (wm + i * 16 + fr) * BK + fq * 8);
#pragma unroll
        for (int j = 0; j < 4; ++j)
            bf[j] = *(const short8*)(Bs + (wn + j * 16 + fr) * BK + fq * 8);

#pragma unroll
        for (int i = 0; i < 4; ++i)
#pragma unroll
            for (int j = 0; j < 4; ++j)
                acc[i][j] = __builtin_amdgcn_mfma_f32_16x16x32_bf16(
                    af[i], bf[j], acc[i][j], 0, 0, 0);

        __syncthreads();
    }

    // epilogue: C/D layout col = lane&15, row = (lane>>4)*4 + r
#pragma unroll
    for (int j = 0; j < 4; ++j) {
        const int ng = n0 + wn + j * 16 + fr;
        const float bv = (EPI == 2) ? 0.0f : bias[(long)e * biasE + ng];
#pragma unroll
        for (int i = 0; i < 4; ++i) {
#pragma unroll
            for (int r = 0; r < 4; ++r) {
                const int mg = m0 + wm + i * 16 + fq * 4 + r;
                const int b  = mg >> 10;
                const int c  = mg & (CAP - 1);
                const long off = (long)b * sOb + (long)e * sOe + (long)c * ldo + ng;
                if (EPI == 0) {
                    ((__hip_bfloat16*)Out)[off] =
                        __float2bfloat16(gelu_tanh(acc[i][j][r] + bv));
                } else if (EPI == 1) {
                    ((float*)Out)[off] = acc[i][j][r] + bv;
                } else {
                    ((float*)Out)[off] += acc[i][j][r];
                }
            }
        }
    }
}

__global__ __launch_bounds__(256) void cvt_f32_bf16(
    const float* __restrict__ in, __hip_bfloat16* __restrict__ out, const long n)
{
    long i = ((long)blockIdx.x * blockDim.x + threadIdx.x) * 4;
    const long stride = (long)gridDim.x * blockDim.x * 4;
    for (; i < n; i += stride) {
        const float4 v = *(const float4*)(in + i);
        __hip_bfloat16 t0 = __float2bfloat16(v.x);
        __hip_bfloat16 t1 = __float2bfloat16(v.y);
        __hip_bfloat16 t2 = __float2bfloat16(v.z);
        __hip_bfloat16 t3 = __float2bfloat16(v.w);
        ushort4 o;
        o.x = *(unsigned short*)&t0;
        o.y = *(unsigned short*)&t1;
        o.z = *(unsigned short*)&t2;
        o.w = *(unsigned short*)&t3;
        *(ushort4*)(out + i) = o;
    }
}

// per-expert transpose (R x Cc) fp32 -> (Cc x R) bf16
__global__ __launch_bounds__(256) void transpose_cvt(
    const float* __restrict__ in, __hip_bfloat16* __restrict__ out,
    const int R, const int Cc)
{
    __shared__ float tile[32][33];
    const int e = blockIdx.z;
    const float* pin = in + (long)e * R * Cc;
    __hip_bfloat16* pout = out + (long)e * R * Cc;
    const int c0 = blockIdx.x * 32;
    const int r0 = blockIdx.y * 32;
    const int tx = threadIdx.x & 31;
    const int ty = threadIdx.x >> 5;  // 0..7
#pragma unroll
    for (int rr = ty; rr < 32; rr += 8)
        tile[rr][tx] = pin[(long)(r0 + rr) * Cc + c0 + tx];
    __syncthreads();
#pragma unroll
    for (int rr = ty; rr < 32; rr += 8)
        pout[(long)(c0 + rr) * R + r0 + tx] = __float2bfloat16(tile[tx][rr]);
}

}  // namespace

extern "C" void kernel_launch(void* const* d_in, const int* in_sizes, int n_in,
                              void* d_out, int out_size, void* d_ws, size_t ws_size,
                              hipStream_t stream) {
    const float* x  = (const float*)d_in[0];
    const float* w1 = (const float*)d_in[1];
    const float* b1 = (const float*)d_in[2];
    const float* w2 = (const float*)d_in[3];
    const float* b2 = (const float*)d_in[4];
    float* out = (float*)d_out;

    const long nX  = (long)BB * EC_ * D_;  // 67,108,864
    const long nW1 = (long)E_ * D_ * F_;   //  8,388,608
    const long nW2 = nW1;

    __hip_bfloat16* xb  = (__hip_bfloat16*)d_ws;
    __hip_bfloat16* w1t = xb + nX;
    __hip_bfloat16* w2t = w1t + nW1;
    __hip_bfloat16* h   = w2t + nW2;

    const size_t fixed = (size_t)(nX + nW1 + nW2) * 2;  // 160 MiB

    // largest F-chunk whose h-buffer fits the workspace
    int Fc = 0;
    for (int cand : {2048, 1024, 512, 256, 128}) {
        size_t need = fixed + (size_t)BB * EC_ * cand * 2;
        if (need <= ws_size) { Fc = cand; break; }
    }
    if (Fc == 0) return;  // workspace too small — fail visibly

    // 1) x -> bf16
    cvt_f32_bf16<<<dim3(32768), dim3(256), 0, stream>>>(x, xb, nX);
    // 2) w1 (E,D,F) -> w1t (E,F,D) bf16
    transpose_cvt<<<dim3(F_ / 32, D_ / 32, E_), dim3(256), 0, stream>>>(w1, w1t, D_, F_);
    // 3) w2 (E,F,D) -> w2t (E,D,F) bf16
    transpose_cvt<<<dim3(D_ / 32, F_ / 32, E_), dim3(256), 0, stream>>>(w2, w2t, F_, D_);

    for (int f0 = 0; f0 < F_; f0 += Fc) {
        // GEMM1 chunk: h(b,e,c, 0..Fc) = gelu(x @ w1[:, f0:f0+Fc] + b1[f0:...])
        gemm_bt<0><<<dim3(Fc / BN, M_ / BM, E_), dim3(256), 0, stream>>>(
            xb, w1t + (long)f0 * D_, b1 + f0, h,
            /*K=*/D_, /*ldb=*/D_, /*ldo=*/Fc,
            /*sAb=*/EC_ * D_, /*sAe=*/(long)CAP * D_,
            /*sBe=*/(long)F_ * D_, /*biasE=*/F_,
            /*sOb=*/(long)E_ * CAP * Fc, /*sOe=*/(long)CAP * Fc);

        // GEMM2 chunk: y (+)= h_chunk @ w2[f0:f0+Fc, :]  (+ b2 on first chunk)
        if (f0 == 0) {
            gemm_bt<1><<<dim3(D_ / BN, M_ / BM, E_), dim3(256), 0, stream>>>(
                h, w2t + f0, b2, out,
                /*K=*/Fc, /*ldb=*/F_, /*ldo=*/D_,
                /*sAb=*/(long)E_ * CAP * Fc, /*sAe=*/(long)CAP * Fc,
                /*sBe=*/(long)D_ * F_, /*biasE=*/D_,
                /*sOb=*/EC_ * D_, /*sOe=*/(long)CAP * D_);
        } else {
            gemm_bt<2><<<dim3(D_ / BN, M_ / BM, E_), dim3(256), 0, stream>>>(
                h, w2t + f0, nullptr, out,
                /*K=*/Fc, /*ldb=*/F_, /*ldo=*/D_,
                /*sAb=*/(long)E_ * CAP * Fc, /*sAe=*/(long)CAP * Fc,
                /*sBe=*/(long)D_ * F_, /*biasE=*/D_,
                /*sOb=*/EC_ * D_, /*sOe=*/(long)CAP * D_);
        }
    }
}